// Round 1
// baseline (263.046 us; speedup 1.0000x reference)
//
#include <hip/hip_runtime.h>
#include <hip/hip_bf16.h>

#define NB 2
#define NS 2048
#define ND 1024
#define NH 16
#define NDH 64
#define NM 4096   // NB*NS

typedef __bf16 bf16;
typedef __bf16 bf16x8 __attribute__((ext_vector_type(8)));
typedef __bf16 bf16x4 __attribute__((ext_vector_type(4)));
typedef float f32x4 __attribute__((ext_vector_type(4)));

#define ASYNC16(g, l) __builtin_amdgcn_global_load_lds( \
    (const __attribute__((address_space(1))) void*)(g), \
    (__attribute__((address_space(3))) void*)(l), 16, 0, 0)

// ---------------------------------------------------------------- convert
__global__ __launch_bounds__(256) void convert_kernel(
    const float* __restrict__ x,
    const float* __restrict__ wq, const float* __restrict__ wk,
    const float* __restrict__ wv, const float* __restrict__ wo,
    bf16* __restrict__ xb, bf16* __restrict__ wb) {
  int i = blockIdx.x * 256 + threadIdx.x;   // float4 index
  const int n_x4 = (NM * ND) / 4;           // 1M
  const int n_w4 = (ND * ND) / 4;           // 256K
  float4 v;
  bf16* dst;
  if (i < n_x4) {
    v = ((const float4*)x)[i];
    dst = xb + (size_t)i * 4;
  } else {
    int j = i - n_x4;
    int w = j / n_w4;
    int o = j - w * n_w4;
    const float* W = (w == 0) ? wq : (w == 1) ? wk : (w == 2) ? wv : wo;
    v = ((const float4*)W)[o];
    dst = wb + (size_t)w * (ND * ND) + (size_t)o * 4;
  }
  bf16x4 o4;
  o4[0] = (bf16)v.x; o4[1] = (bf16)v.y; o4[2] = (bf16)v.z; o4[3] = (bf16)v.w;
  *(bf16x4*)dst = o4;
}

// ---------------------------------------------------------------- gemm_bt
// C[M,N] = A[M,K] * B[N,K]^T, bf16 in, fp32 acc.
// EPI 0: write bf16 natural layout at Cbase + z*M*N elements (QKV)
// EPI 1: write fp32 natural layout (final output)
template <int EPI>
__global__ __launch_bounds__(256) void gemm_bt(
    const bf16* __restrict__ A, const bf16* __restrict__ Bmat,
    void* __restrict__ Cbase, int Mm, int Nn, int Kk) {
  __shared__ bf16 As[128 * 64];
  __shared__ bf16 Bs[128 * 64];
  const int t = threadIdx.x;
  const int lane = t & 63, w = t >> 6;
  const int wr = w >> 1, wc = w & 1;
  const int bm = blockIdx.y * 128;
  const int bn = blockIdx.x * 128;
  const bf16* Bz = Bmat + (size_t)blockIdx.z * Nn * Kk;

  f32x4 acc[4][4];
#pragma unroll
  for (int i = 0; i < 4; ++i)
#pragma unroll
    for (int j = 0; j < 4; ++j) acc[i][j] = (f32x4){0.f, 0.f, 0.f, 0.f};

  for (int kt = 0; kt < Kk / 64; ++kt) {
    __syncthreads();
#pragma unroll
    for (int i = 0; i < 4; ++i) {
      int c = w * 64 + lane + i * 256;      // 16B chunk id, 0..1023
      int row = c >> 3;
      int js = (c & 7) ^ (row & 7);         // inverse-swizzled source chunk
      ASYNC16(A + (size_t)(bm + row) * Kk + kt * 64 + js * 8, As + c * 8);
      ASYNC16(Bz + (size_t)(bn + row) * Kk + kt * 64 + js * 8, Bs + c * 8);
    }
    __syncthreads();
#pragma unroll
    for (int ks = 0; ks < 2; ++ks) {
      const int kb = ks * 64 + (lane >> 4) * 16;  // byte offset in 128B row
      bf16x8 af[4], bfr[4];
#pragma unroll
      for (int i = 0; i < 4; ++i) {
        int ra = wr * 64 + i * 16 + (lane & 15);
        af[i] = *(const bf16x8*)((const char*)As + ra * 128 + (kb ^ ((ra & 7) << 4)));
        int rb = wc * 64 + i * 16 + (lane & 15);
        bfr[i] = *(const bf16x8*)((const char*)Bs + rb * 128 + (kb ^ ((rb & 7) << 4)));
      }
#pragma unroll
      for (int i = 0; i < 4; ++i)
#pragma unroll
        for (int j = 0; j < 4; ++j)
          acc[i][j] = __builtin_amdgcn_mfma_f32_16x16x32_bf16(af[i], bfr[j], acc[i][j], 0, 0, 0);
    }
  }

  const int row0 = bm + wr * 64;
  const int col0 = bn + wc * 64;
#pragma unroll
  for (int i = 0; i < 4; ++i)
#pragma unroll
    for (int j = 0; j < 4; ++j) {
      int r = row0 + i * 16 + (lane >> 4) * 4;
      int ccol = col0 + j * 16 + (lane & 15);
#pragma unroll
      for (int q = 0; q < 4; ++q) {
        size_t idx = (size_t)(r + q) * Nn + ccol;
        if (EPI == 0)
          ((bf16*)Cbase)[(size_t)blockIdx.z * Mm * Nn + idx] = (bf16)acc[i][j][q];
        else
          ((float*)Cbase)[idx] = acc[i][j][q];
      }
    }
}

// ---------------------------------------------------------------- rope
// reads raw q/k bf16 [NM, ND], applies RoPE per head in fp32,
// writes [B,H,S,Dh] bf16.  Q additionally scaled by 1/sqrt(Dh)=0.125.
__global__ __launch_bounds__(256) void rope_kernel(
    const bf16* __restrict__ qraw, const bf16* __restrict__ kraw,
    bf16* __restrict__ Qr, bf16* __restrict__ Kr) {
  int t = blockIdx.x * 256 + threadIdx.x;  // 2 * 2^21 threads
  int which = t >> 21;
  int r = t & ((1 << 21) - 1);
  int d = r & 31;
  int s = (r >> 5) & 2047;
  int bh = r >> 16;                        // 0..31
  int b = bh >> 4, h = bh & 15;
  const bf16* src = which ? kraw : qraw;
  bf16* dst = which ? Kr : Qr;
  size_t si = ((size_t)(b * NS + s)) * ND + h * NDH + d;
  float x1 = (float)src[si];
  float x2 = (float)src[si + 32];
  // inv_freq = 10000^(-d/32) = 2^(-d/32 * log2(10000))
  float invf = exp2f(-13.28771237954945f * ((float)d * (1.0f / 32.0f)));
  float f = (float)s * invf;
  float sn, c;
  sincosf(f, &sn, &c);
  float scale = which ? 1.0f : 0.125f;
  size_t di = ((size_t)bh * NS + s) * NDH + d;
  dst[di]      = (bf16)((x1 * c - x2 * sn) * scale);
  dst[di + 32] = (bf16)((x2 * c + x1 * sn) * scale);
}

// ---------------------------------------------------------------- V^T
// vraw bf16 [NM, ND] -> VT bf16 [B,H,Dh,S]
__global__ __launch_bounds__(256) void transv_kernel(
    const bf16* __restrict__ vraw, bf16* __restrict__ VT) {
  __shared__ bf16 tl[64][65];
  int s0 = blockIdx.x * 64;
  int bh = blockIdx.y;
  int b = bh >> 4, h = bh & 15;
  int t = threadIdx.x;
#pragma unroll
  for (int i = 0; i < 4; ++i) {
    int row = (t >> 4) + i * 16;           // s_local
    int d4 = (t & 15) * 4;
    *(bf16x4*)&tl[row][d4] =
        *(const bf16x4*)&vraw[((size_t)(b * NS + s0 + row)) * ND + h * NDH + d4];
  }
  __syncthreads();
#pragma unroll
  for (int i = 0; i < 4; ++i) {
    int dr = (t >> 4) + i * 16;            // d_local
    int s4 = (t & 15) * 4;
    bf16x4 o;
    o[0] = tl[s4 + 0][dr]; o[1] = tl[s4 + 1][dr];
    o[2] = tl[s4 + 2][dr]; o[3] = tl[s4 + 3][dr];
    *(bf16x4*)&VT[((size_t)(bh * NDH + dr)) * NS + s0 + s4] = o;
  }
}

// ---------------------------------------------------------------- attention
// Qr,Kr [B,H,S,Dh] bf16 (Q pre-scaled by 0.125), VT [B,H,Dh,S] bf16.
// out bf16 [B,S,H*Dh].  4 waves x 16 q-rows, KBLK=64, online softmax.
__global__ __launch_bounds__(256) void attn_kernel(
    const bf16* __restrict__ Qr, const bf16* __restrict__ Kr,
    const bf16* __restrict__ VT, bf16* __restrict__ out) {
  __shared__ bf16 Ks[64 * 64];
  __shared__ bf16 Vs[64 * 64];             // [d][key]
  __shared__ bf16 Ps[4 * 16 * 64];         // per-wave P tile
  const int t = threadIdx.x, lane = t & 63, w = t >> 6;
  const int bh = blockIdx.y;
  const int q0 = blockIdx.x * 64 + w * 16;
  const bf16* Qbase = Qr + ((size_t)bh * NS + q0) * NDH;

  bf16x8 qf[2];
  {
    int qr = lane & 15;
    int ko = (lane >> 4) * 8;
    qf[0] = *(const bf16x8*)(Qbase + (size_t)qr * NDH + ko);
    qf[1] = *(const bf16x8*)(Qbase + (size_t)qr * NDH + 32 + ko);
  }

  f32x4 o[4];
#pragma unroll
  for (int i = 0; i < 4; ++i) o[i] = (f32x4){0.f, 0.f, 0.f, 0.f};
  float mrow[4], lrow[4];
#pragma unroll
  for (int j = 0; j < 4; ++j) { mrow[j] = -1e30f; lrow[j] = 0.f; }

  for (int kt = 0; kt < NS / 64; ++kt) {
    __syncthreads();
#pragma unroll
    for (int i = 0; i < 2; ++i) {
      int c = w * 64 + lane + i * 256;     // 0..511
      int row = c >> 3;
      int js = (c & 7) ^ (row & 7);
      ASYNC16(Kr + ((size_t)bh * NS + kt * 64 + row) * NDH + js * 8, Ks + c * 8);
      ASYNC16(VT + ((size_t)bh * NDH + row) * NS + kt * 64 + js * 8, Vs + c * 8);
    }
    __syncthreads();

    // S = Q K^T  (scores; Q pre-scaled)
    f32x4 sc[4];
#pragma unroll
    for (int nf = 0; nf < 4; ++nf) sc[nf] = (f32x4){0.f, 0.f, 0.f, 0.f};
#pragma unroll
    for (int ks = 0; ks < 2; ++ks) {
      const int kb = ks * 64 + (lane >> 4) * 16;
#pragma unroll
      for (int nf = 0; nf < 4; ++nf) {
        int rk = nf * 16 + (lane & 15);
        bf16x8 kf = *(const bf16x8*)((const char*)Ks + rk * 128 + (kb ^ ((rk & 7) << 4)));
        sc[nf] = __builtin_amdgcn_mfma_f32_16x16x32_bf16(qf[ks], kf, sc[nf], 0, 0, 0);
      }
    }

    // online softmax (rows owned by 16-lane groups)
    float pv[4][4], scl[4];
#pragma unroll
    for (int j = 0; j < 4; ++j) {
      float mx = fmaxf(fmaxf(sc[0][j], sc[1][j]), fmaxf(sc[2][j], sc[3][j]));
#pragma unroll
      for (int off = 1; off < 16; off <<= 1) mx = fmaxf(mx, __shfl_xor(mx, off, 64));
      float mnew = fmaxf(mrow[j], mx);
      scl[j] = __expf(mrow[j] - mnew);
      float sum = 0.f;
#pragma unroll
      for (int nf = 0; nf < 4; ++nf) {
        float p = __expf(sc[nf][j] - mnew);
        pv[nf][j] = p;
        sum += p;
      }
#pragma unroll
      for (int off = 1; off < 16; off <<= 1) sum += __shfl_xor(sum, off, 64);
      lrow[j] = lrow[j] * scl[j] + sum;
      mrow[j] = mnew;
    }

    // write P (bf16, swizzled) to per-wave LDS region; rescale O
#pragma unroll
    for (int j = 0; j < 4; ++j) {
      int r = (lane >> 4) * 4 + j;
      char* base = (char*)Ps + w * 2048 + r * 128;
#pragma unroll
      for (int nf = 0; nf < 4; ++nf) {
        int key = nf * 16 + (lane & 15);
        *(bf16*)(base + ((key * 2) ^ ((r & 7) << 4))) = (bf16)pv[nf][j];
      }
    }
#pragma unroll
    for (int df = 0; df < 4; ++df)
#pragma unroll
      for (int j = 0; j < 4; ++j) o[df][j] *= scl[j];

    // O += P V  (A = P from LDS, B = VT tile)
#pragma unroll
    for (int ks = 0; ks < 2; ++ks) {
      const int kb = ks * 64 + (lane >> 4) * 16;
      int rp = lane & 15;
      bf16x8 pf = *(const bf16x8*)((const char*)Ps + w * 2048 + rp * 128 + (kb ^ ((rp & 7) << 4)));
#pragma unroll
      for (int df = 0; df < 4; ++df) {
        int rv = df * 16 + (lane & 15);
        bf16x8 vf = *(const bf16x8*)((const char*)Vs + rv * 128 + (kb ^ ((rv & 7) << 4)));
        o[df] = __builtin_amdgcn_mfma_f32_16x16x32_bf16(pf, vf, o[df], 0, 0, 0);
      }
    }
  }

  // epilogue: divide by l, write [B,S,H*Dh] bf16
  const int b = bh >> 4, h = bh & 15;
#pragma unroll
  for (int df = 0; df < 4; ++df)
#pragma unroll
    for (int j = 0; j < 4; ++j) {
      int srow = q0 + (lane >> 4) * 4 + j;
      int d = df * 16 + (lane & 15);
      out[((size_t)(b * NS + srow)) * ND + h * NDH + d] = (bf16)(o[df][j] / lrow[j]);
    }
}

// ---------------------------------------------------------------- launch
extern "C" void kernel_launch(void* const* d_in, const int* in_sizes, int n_in,
                              void* d_out, int out_size, void* d_ws, size_t ws_size,
                              hipStream_t stream) {
  const float* x  = (const float*)d_in[0];
  const float* wq = (const float*)d_in[1];
  const float* wk = (const float*)d_in[2];
  const float* wv = (const float*)d_in[3];
  const float* wo = (const float*)d_in[4];
  char* ws = (char*)d_ws;
  bf16* xb   = (bf16*)(ws);                      // 8MB  [4096,1024]
  bf16* wb   = (bf16*)(ws + (8u << 20));         // 8MB  Wq|Wk|Wv|Wo [1024,1024] each
  bf16* qkv  = (bf16*)(ws + (16u << 20));        // 24MB raw q|k|v [4096,1024] each
  bf16* Qr   = (bf16*)(ws + (40u << 20));        // 8MB  [B,H,S,Dh]
  bf16* Kr   = (bf16*)(ws + (48u << 20));        // 8MB  [B,H,S,Dh]
  bf16* VT   = (bf16*)(ws + (56u << 20));        // 8MB  [B,H,Dh,S]
  bf16* attn = (bf16*)(ws + (64u << 20));        // 8MB  [B,S,H*Dh]
  float* out = (float*)d_out;

  convert_kernel<<<8192, 256, 0, stream>>>(x, wq, wk, wv, wo, xb, wb);
  gemm_bt<0><<<dim3(8, 32, 3), 256, 0, stream>>>(xb, wb, (void*)qkv, NM, ND, ND);
  rope_kernel<<<16384, 256, 0, stream>>>(qkv, qkv + (size_t)NM * ND, Qr, Kr);
  transv_kernel<<<dim3(32, 32), 256, 0, stream>>>(qkv + (size_t)2 * NM * ND, VT);
  attn_kernel<<<dim3(32, 32), 256, 0, stream>>>(Qr, Kr, VT, attn);
  gemm_bt<1><<<dim3(8, 32, 1), 256, 0, stream>>>(attn, wb + 3 * ND * ND, (void*)out, NM, ND, ND);
}

// Round 3
// 215.966 us; speedup vs baseline: 1.2180x; 1.2180x over previous
//
#include <hip/hip_runtime.h>
#include <hip/hip_bf16.h>

#define NB 2
#define NS 2048
#define ND 1024
#define NH 16
#define NDH 64
#define NM 4096   // NB*NS

typedef __bf16 bf16;
typedef __bf16 bf16x8 __attribute__((ext_vector_type(8)));
typedef __bf16 bf16x4 __attribute__((ext_vector_type(4)));
typedef float f32x4 __attribute__((ext_vector_type(4)));
typedef float f32x16 __attribute__((ext_vector_type(16)));

#define ASYNC16(g, l) __builtin_amdgcn_global_load_lds( \
    (const __attribute__((address_space(1))) void*)(g), \
    (__attribute__((address_space(3))) void*)(l), 16, 0, 0)

static __device__ __forceinline__ unsigned cvt_pk_bf16(float a, float b) {
  unsigned r;
  asm("v_cvt_pk_bf16_f32 %0, %1, %2" : "=v"(r) : "v"(a), "v"(b));
  return r;
}

// ---------------------------------------------------------------- convert
__global__ __launch_bounds__(256) void convert_kernel(
    const float* __restrict__ x,
    const float* __restrict__ wq, const float* __restrict__ wk,
    const float* __restrict__ wv, const float* __restrict__ wo,
    bf16* __restrict__ xb, bf16* __restrict__ wb) {
  int i = blockIdx.x * 256 + threadIdx.x;   // float4 index
  const int n_x4 = (NM * ND) / 4;           // 1M
  const int n_w4 = (ND * ND) / 4;           // 256K
  float4 v;
  bf16* dst;
  if (i < n_x4) {
    v = ((const float4*)x)[i];
    dst = xb + (size_t)i * 4;
  } else {
    int j = i - n_x4;
    int w = j / n_w4;
    int o = j - w * n_w4;
    const float* W = (w == 0) ? wq : (w == 1) ? wk : (w == 2) ? wv : wo;
    v = ((const float4*)W)[o];
    dst = wb + (size_t)w * (ND * ND) + (size_t)o * 4;
  }
  bf16x4 o4;
  o4[0] = (bf16)v.x; o4[1] = (bf16)v.y; o4[2] = (bf16)v.z; o4[3] = (bf16)v.w;
  *(bf16x4*)dst = o4;
}

// ---------------------------------------------------------------- rope table
// tab[s*32+d] = {cos(s*invf(d)), sin(s*invf(d))}, d in [0,32)
__global__ __launch_bounds__(256) void tab_kernel(float2* __restrict__ tab) {
  int t = blockIdx.x * 256 + threadIdx.x;   // 65536
  int s = t >> 5, d = t & 31;
  float invf = exp2f(-0.4152410118609203f * (float)d);  // 10000^(-d/32)
  float f = (float)s * invf;
  float sn, cs;
  sincosf(f, &sn, &cs);
  tab[t] = make_float2(cs, sn);
}

// ---------------------------------------------------------------- gemm QKV
// C[M,N] = A[M,K] * B[N,K]^T per z in {Q,K,V}; RoPE fused for z<2.
__global__ __launch_bounds__(256) void gemm_qkv(
    const bf16* __restrict__ A, const bf16* __restrict__ Bmat,
    bf16* __restrict__ Qr, bf16* __restrict__ Kr, bf16* __restrict__ vraw,
    const float2* __restrict__ tab) {
  __shared__ bf16 As[128 * 64];
  __shared__ bf16 Bs[128 * 64];
  const int t = threadIdx.x;
  const int lane = t & 63, w = t >> 6;
  const int wr = w >> 1, wc = w & 1;
  const int bm = blockIdx.y * 128;
  const int bn = blockIdx.x * 128;
  const int z = blockIdx.z;
  const bf16* Bz = Bmat + (size_t)z * ND * ND;

  f32x4 acc[4][4];
#pragma unroll
  for (int i = 0; i < 4; ++i)
#pragma unroll
    for (int j = 0; j < 4; ++j) acc[i][j] = (f32x4){0.f, 0.f, 0.f, 0.f};

  for (int kt = 0; kt < ND / 64; ++kt) {
    __syncthreads();
#pragma unroll
    for (int i = 0; i < 4; ++i) {
      int c = w * 64 + lane + i * 256;
      int row = c >> 3;
      int js = (c & 7) ^ (row & 7);
      ASYNC16(A + (size_t)(bm + row) * ND + kt * 64 + js * 8, As + c * 8);
      ASYNC16(Bz + (size_t)(bn + row) * ND + kt * 64 + js * 8, Bs + c * 8);
    }
    __syncthreads();
#pragma unroll
    for (int ks = 0; ks < 2; ++ks) {
      const int kb = ks * 64 + (lane >> 4) * 16;
      bf16x8 af[4], bfr[4];
#pragma unroll
      for (int i = 0; i < 4; ++i) {
        int ra = wr * 64 + i * 16 + (lane & 15);
        af[i] = *(const bf16x8*)((const char*)As + ra * 128 + (kb ^ ((ra & 7) << 4)));
        int rb = wc * 64 + i * 16 + (lane & 15);
        bfr[i] = *(const bf16x8*)((const char*)Bs + rb * 128 + (kb ^ ((rb & 7) << 4)));
      }
#pragma unroll
      for (int i = 0; i < 4; ++i)
#pragma unroll
        for (int j = 0; j < 4; ++j)
          acc[i][j] = __builtin_amdgcn_mfma_f32_16x16x32_bf16(af[i], bfr[j], acc[i][j], 0, 0, 0);
    }
  }

  const int row0 = bm + wr * 64;
  const int col0 = bn + wc * 64;
  if (z == 2) {
#pragma unroll
    for (int i = 0; i < 4; ++i)
#pragma unroll
      for (int j = 0; j < 4; ++j) {
        int r = row0 + i * 16 + (lane >> 4) * 4;
        int ccol = col0 + j * 16 + (lane & 15);
#pragma unroll
        for (int q = 0; q < 4; ++q)
          vraw[(size_t)(r + q) * ND + ccol] = (bf16)acc[i][j][q];
      }
  } else {
    bf16* dst = z ? Kr : Qr;
    const float qs = z ? 1.0f : 0.125f;
    const int h = col0 >> 6;
    const int ln15 = lane & 15;
#pragma unroll
    for (int i = 0; i < 4; ++i)
#pragma unroll
      for (int j = 0; j < 2; ++j)
#pragma unroll
        for (int q = 0; q < 4; ++q) {
          int r = row0 + i * 16 + (lane >> 4) * 4 + q;
          int b = r >> 11, s = r & (NS - 1);
          int d1 = j * 16 + ln15;
          float2 tc = tab[s * 32 + d1];
          float x1 = acc[i][j][q], x2 = acc[i][j + 2][q];
          size_t base = ((size_t)((b * NH + h) * NS + s)) * NDH;
          dst[base + d1]      = (bf16)((x1 * tc.x - x2 * tc.y) * qs);
          dst[base + d1 + 32] = (bf16)((x2 * tc.x + x1 * tc.y) * qs);
        }
  }
}

// ---------------------------------------------------------------- gemm out
// out[M,N] = A[M,K] * Wo[N,K]^T, fp32 output
__global__ __launch_bounds__(256) void gemm_out(
    const bf16* __restrict__ A, const bf16* __restrict__ Bmat,
    float* __restrict__ Cout) {
  __shared__ bf16 As[128 * 64];
  __shared__ bf16 Bs[128 * 64];
  const int t = threadIdx.x;
  const int lane = t & 63, w = t >> 6;
  const int wr = w >> 1, wc = w & 1;
  const int bm = blockIdx.y * 128;
  const int bn = blockIdx.x * 128;

  f32x4 acc[4][4];
#pragma unroll
  for (int i = 0; i < 4; ++i)
#pragma unroll
    for (int j = 0; j < 4; ++j) acc[i][j] = (f32x4){0.f, 0.f, 0.f, 0.f};

  for (int kt = 0; kt < ND / 64; ++kt) {
    __syncthreads();
#pragma unroll
    for (int i = 0; i < 4; ++i) {
      int c = w * 64 + lane + i * 256;
      int row = c >> 3;
      int js = (c & 7) ^ (row & 7);
      ASYNC16(A + (size_t)(bm + row) * ND + kt * 64 + js * 8, As + c * 8);
      ASYNC16(Bmat + (size_t)(bn + row) * ND + kt * 64 + js * 8, Bs + c * 8);
    }
    __syncthreads();
#pragma unroll
    for (int ks = 0; ks < 2; ++ks) {
      const int kb = ks * 64 + (lane >> 4) * 16;
      bf16x8 af[4], bfr[4];
#pragma unroll
      for (int i = 0; i < 4; ++i) {
        int ra = wr * 64 + i * 16 + (lane & 15);
        af[i] = *(const bf16x8*)((const char*)As + ra * 128 + (kb ^ ((ra & 7) << 4)));
        int rb = wc * 64 + i * 16 + (lane & 15);
        bfr[i] = *(const bf16x8*)((const char*)Bs + rb * 128 + (kb ^ ((rb & 7) << 4)));
      }
#pragma unroll
      for (int i = 0; i < 4; ++i)
#pragma unroll
        for (int j = 0; j < 4; ++j)
          acc[i][j] = __builtin_amdgcn_mfma_f32_16x16x32_bf16(af[i], bfr[j], acc[i][j], 0, 0, 0);
    }
  }

  const int row0 = bm + wr * 64;
  const int col0 = bn + wc * 64;
#pragma unroll
  for (int i = 0; i < 4; ++i)
#pragma unroll
    for (int j = 0; j < 4; ++j) {
      int r = row0 + i * 16 + (lane >> 4) * 4;
      int ccol = col0 + j * 16 + (lane & 15);
#pragma unroll
      for (int q = 0; q < 4; ++q)
        Cout[(size_t)(r + q) * ND + ccol] = acc[i][j][q];
    }
}

// ---------------------------------------------------------------- V^T
// vraw bf16 [NM, ND] -> VT bf16 [B,H,Dh,S]
__global__ __launch_bounds__(256) void transv_kernel(
    const bf16* __restrict__ vraw, bf16* __restrict__ VT) {
  __shared__ bf16 tl[64][65];
  int s0 = blockIdx.x * 64;
  int bh = blockIdx.y;
  int b = bh >> 4, h = bh & 15;
  int t = threadIdx.x;
#pragma unroll
  for (int i = 0; i < 4; ++i) {
    int row = (t >> 4) + i * 16;
    int d4 = (t & 15) * 4;
    *(bf16x4*)&tl[row][d4] =
        *(const bf16x4*)&vraw[((size_t)(b * NS + s0 + row)) * ND + h * NDH + d4];
  }
  __syncthreads();
#pragma unroll
  for (int i = 0; i < 4; ++i) {
    int dr = (t >> 4) + i * 16;
    int s4 = (t & 15) * 4;
    bf16x4 o;
    o[0] = tl[s4 + 0][dr]; o[1] = tl[s4 + 1][dr];
    o[2] = tl[s4 + 2][dr]; o[3] = tl[s4 + 3][dr];
    *(bf16x4*)&VT[((size_t)(bh * NDH + dr)) * NS + s0 + s4] = o;
  }
}

// ---------------------------------------------------------------- attention
// Swapped-QK (mfma(K,Q)) in-register-softmax flash attention.
// 4 waves x 32 q-rows (QBLK=128/block), KVBLK=64, double-buffered LDS.
// Qr pre-scaled by 0.125.  Score C-layout: col=lane&31=query,
// row=(reg&3)+8*(reg>>2)+4*(lane>>5)=key  [m74/m101 verified].
__global__ __launch_bounds__(256) void attn_kernel(
    const bf16* __restrict__ Qr, const bf16* __restrict__ Kr,
    const bf16* __restrict__ VT, bf16* __restrict__ out) {
  __shared__ bf16 Ks[2][64 * 64];
  __shared__ bf16 Vs[2][64 * 64];   // rows = d, cols = key
  const int t = threadIdx.x, lane = t & 63, w = t >> 6;
  const int hi = lane >> 5, ln = lane & 31;
  // XCD-bijective swizzle (512 blocks, 512%8==0): same-bh blocks share an XCD L2
  int wg = blockIdx.x;
  int sw = (wg & 7) * 64 + (wg >> 3);
  const int qb = sw & 15, bh = sw >> 4;
  const int q0 = qb * 128 + w * 32;

  // Q fragment: B-operand, col=query=ln, k=d=(hi*8+i)+16c
  bf16x8 qv[4];
  {
    const bf16* Qb = Qr + ((size_t)bh * NS + q0 + ln) * NDH + hi * 8;
#pragma unroll
    for (int c = 0; c < 4; ++c) qv[c] = *(const bf16x8*)(Qb + c * 16);
  }

  f32x16 O0, O1;
#pragma unroll
  for (int r = 0; r < 16; ++r) { O0[r] = 0.f; O1[r] = 0.f; }
  float m = -1e30f, l = 0.f;

  // prologue: stage tile 0 into buf 0
#pragma unroll
  for (int i = 0; i < 2; ++i) {
    int ch = t + i * 256;
    int row = ch >> 3, js = (ch & 7) ^ (row & 7);
    ASYNC16(Kr + ((size_t)bh * NS + row) * NDH + js * 8, &Ks[0][ch * 8]);
    ASYNC16(VT + ((size_t)bh * NDH + row) * NS + js * 8, &Vs[0][ch * 8]);
  }
  __syncthreads();

  int cur = 0;
  for (int kt = 0; kt < NS / 64; ++kt) {
    if (kt + 1 < NS / 64) {     // issue next-tile loads before compute (T3 min)
      int nb = cur ^ 1;
#pragma unroll
      for (int i = 0; i < 2; ++i) {
        int ch = t + i * 256;
        int row = ch >> 3, js = (ch & 7) ^ (row & 7);
        ASYNC16(Kr + ((size_t)bh * NS + (kt + 1) * 64 + row) * NDH + js * 8, &Ks[nb][ch * 8]);
        ASYNC16(VT + ((size_t)bh * NDH + row) * NS + (kt + 1) * 64 + js * 8, &Vs[nb][ch * 8]);
      }
    }
    const char* Kb = (const char*)Ks[cur];
    const char* Vb = (const char*)Vs[cur];

    // S = K Q^T (swapped): lane owns full 64-key row for query ln (with pair lane^32)
    f32x16 s0, s1;
#pragma unroll
    for (int r = 0; r < 16; ++r) { s0[r] = 0.f; s1[r] = 0.f; }
#pragma unroll
    for (int c = 0; c < 4; ++c) {
      int ko = c * 32 + hi * 16;
      int r0 = ln, r1 = 32 + ln;
      bf16x8 k0 = *(const bf16x8*)(Kb + r0 * 128 + (ko ^ ((r0 & 7) << 4)));
      bf16x8 k1 = *(const bf16x8*)(Kb + r1 * 128 + (ko ^ ((r1 & 7) << 4)));
      s0 = __builtin_amdgcn_mfma_f32_32x32x16_bf16(k0, qv[c], s0, 0, 0, 0);
      s1 = __builtin_amdgcn_mfma_f32_32x32x16_bf16(k1, qv[c], s1, 0, 0, 0);
    }

    // row max: 31 in-lane fmax + one half-swap
    float pmax = s0[0];
#pragma unroll
    for (int r = 1; r < 16; ++r) pmax = fmaxf(pmax, s0[r]);
#pragma unroll
    for (int r = 0; r < 16; ++r) pmax = fmaxf(pmax, s1[r]);
    pmax = fmaxf(pmax, __shfl_xor(pmax, 32, 64));

    // defer-max (T13): rescale only when max grew past threshold
    if (!__all(pmax - m <= 8.0f)) {
      float mnew = fmaxf(m, pmax);
      float scl = __expf(m - mnew);
      m = mnew; l *= scl;
#pragma unroll
      for (int r = 0; r < 16; ++r) { O0[r] *= scl; O1[r] *= scl; }
    }

    float p0[16], p1[16], sum = 0.f;
#pragma unroll
    for (int r = 0; r < 16; ++r) { p0[r] = __expf(s0[r] - m); sum += p0[r]; }
#pragma unroll
    for (int r = 0; r < 16; ++r) { p1[r] = __expf(s1[r] - m); sum += p1[r]; }
    sum += __shfl_xor(sum, 32, 64);
    l += sum;

    // P -> bf16 A-fragments in-register (T12): pack pairs, swap halves
    unsigned u0[8], u1[8], x0[8], x1[8];
#pragma unroll
    for (int g = 0; g < 4; ++g) {
      u0[g]     = cvt_pk_bf16(p0[4 * g],     p0[4 * g + 1]);
      u1[g]     = cvt_pk_bf16(p0[4 * g + 2], p0[4 * g + 3]);
      u0[4 + g] = cvt_pk_bf16(p1[4 * g],     p1[4 * g + 1]);
      u1[4 + g] = cvt_pk_bf16(p1[4 * g + 2], p1[4 * g + 3]);
    }
#pragma unroll
    for (int g = 0; g < 8; ++g) {
      x0[g] = __shfl_xor(u0[g], 32, 64);
      x1[g] = __shfl_xor(u1[g], 32, 64);
    }

    // O += P V   (A=P row=query, k=key; B=VT rows=d)
#pragma unroll
    for (int c = 0; c < 4; ++c) {
      int base = (c >> 1) * 4 + (c & 1) * 2;   // kk*4 + even-group
      union { unsigned u[4]; bf16x8 v; } pa;
      pa.u[0] = hi ? x0[base + 1] : u0[base];
      pa.u[1] = hi ? x1[base + 1] : u1[base];
      pa.u[2] = hi ? u0[base + 1] : x0[base];
      pa.u[3] = hi ? u1[base + 1] : x1[base];
      int ko = c * 32 + hi * 16;
      int rv0 = ln, rv1 = 32 + ln;
      bf16x8 v0 = *(const bf16x8*)(Vb + rv0 * 128 + (ko ^ ((rv0 & 7) << 4)));
      bf16x8 v1 = *(const bf16x8*)(Vb + rv1 * 128 + (ko ^ ((rv1 & 7) << 4)));
      O0 = __builtin_amdgcn_mfma_f32_32x32x16_bf16(pa.v, v0, O0, 0, 0, 0);
      O1 = __builtin_amdgcn_mfma_f32_32x32x16_bf16(pa.v, v1, O1, 0, 0, 0);
    }

    __syncthreads();   // drains vmcnt (next-tile loads) + barrier
    cur ^= 1;
  }

  // epilogue: O row=query=(reg&3)+8*(reg>>2)+4*hi, col=d=nt*32+ln
  float rl = 1.0f / l;
  const int b = bh >> 4, h = bh & 15;
#pragma unroll
  for (int r = 0; r < 16; ++r) {
    int q = (r & 3) + 8 * (r >> 2) + 4 * hi;
    float rlq = __shfl(rl, q, 64);
    int s = q0 + q;
    size_t base = ((size_t)(b * NS + s)) * ND + h * NDH + ln;
    out[base]      = (bf16)(O0[r] * rlq);
    out[base + 32] = (bf16)(O1[r] * rlq);
  }
}

// ---------------------------------------------------------------- launch
extern "C" void kernel_launch(void* const* d_in, const int* in_sizes, int n_in,
                              void* d_out, int out_size, void* d_ws, size_t ws_size,
                              hipStream_t stream) {
  const float* x  = (const float*)d_in[0];
  const float* wq = (const float*)d_in[1];
  const float* wk = (const float*)d_in[2];
  const float* wv = (const float*)d_in[3];
  const float* wo = (const float*)d_in[4];
  char* ws = (char*)d_ws;
  bf16* xb    = (bf16*)(ws);                     // 8MB [4096,1024]
  bf16* wb    = (bf16*)(ws + (8u << 20));        // 8MB Wq|Wk|Wv|Wo
  bf16* vraw  = (bf16*)(ws + (16u << 20));       // 8MB [4096,1024]
  bf16* Qr    = (bf16*)(ws + (24u << 20));       // 8MB [B,H,S,Dh] (pre-scaled)
  bf16* Kr    = (bf16*)(ws + (32u << 20));       // 8MB [B,H,S,Dh]
  bf16* VT    = (bf16*)(ws + (40u << 20));       // 8MB [B,H,Dh,S]
  bf16* attnb = (bf16*)(ws + (48u << 20));       // 8MB [B,S,H*Dh]
  float2* tab = (float2*)(ws + (56u << 20));     // 512KB [2048][32]
  float* out  = (float*)d_out;

  convert_kernel<<<8192, 256, 0, stream>>>(x, wq, wk, wv, wo, xb, wb);
  tab_kernel<<<256, 256, 0, stream>>>(tab);
  gemm_qkv<<<dim3(8, 32, 3), 256, 0, stream>>>(xb, wb, Qr, Kr, vraw, tab);
  transv_kernel<<<dim3(32, 32), 256, 0, stream>>>(vraw, VT);
  attn_kernel<<<dim3(512), 256, 0, stream>>>(Qr, Kr, VT, attnb);
  gemm_out<<<dim3(8, 32), 256, 0, stream>>>(attnb, wb + 3 * ND * ND, out);
}